// Round 1
// baseline (379.589 us; speedup 1.0000x reference)
//
#include <hip/hip_runtime.h>

#define B_ROWS 262144
#define T_COLS 80
#define STEPS 30
#define DT 0.1f
#define RPB 256          // one row per thread
#define THREADS 256

__global__ __launch_bounds__(THREADS) void traj_idm_kernel(
    const float* __restrict__ params,
    const float* __restrict__ sv_v1,
    const float* __restrict__ h1,
    const float* __restrict__ dv1,
    const float* __restrict__ sv_Y1,
    const float* __restrict__ lv_Y_seq1,
    const float* __restrict__ lv_v_seq1,
    float* __restrict__ out)
{
    // LDS only for output transpose (coalesced store). 30.7 KB -> 5 blocks/CU.
    __shared__ __align__(16) float sOut[RPB * STEPS];

    const int t = threadIdx.x;
    const long row = (long)blockIdx.x * RPB + t;
    const long rb  = row * T_COLS;

    // --- per-thread loads of this row's data. cols 48..79 = bytes 192..319:
    // two 64B lines per array, fully consumed -> identical HBM traffic to a
    // coalesced staged load, but no LDS, no barrier, 20 loads in flight/lane.
    const float4* py = (const float4*)(lv_Y_seq1 + rb + 48);   // 16B aligned
    const float4* pv = (const float4*)(lv_v_seq1 + rb + 48);

    float fy[32], fv[32];
    #pragma unroll
    for (int i = 0; i < 8; ++i) {
        const float4 dy = py[i];
        const float4 dv4 = pv[i];
        fy[4*i + 0] = dy.x;  fy[4*i + 1] = dy.y;
        fy[4*i + 2] = dy.z;  fy[4*i + 3] = dy.w;
        fv[4*i + 0] = dv4.x; fv[4*i + 1] = dv4.y;
        fv[4*i + 2] = dv4.z; fv[4*i + 3] = dv4.w;
    }

    float v    = sv_v1[rb + 49];
    float gap  = h1   [rb + 49];
    float delv = dv1  [rb + 49];
    float y    = sv_Y1[rb + 49];

    const float s0  = params[0];
    const float Thw = params[1];
    const float pa  = params[2];
    const float pb  = params[3];
    const float v0  = params[4];
    const float inv2sab = 1.0f / (2.0f * sqrtf(pa * pb));
    const float inv_v0  = 1.0f / v0;
    const float inv_dt  = 1.0f / DT;

    // --- 30-step IDM recurrence, fully unrolled, all indices static ---
    #pragma unroll
    for (int s = 0; s < STEPS; ++s) {
        const float lvY_i = fy[s + 2];   // col 50+s (48-based local index)
        const float lvv_i = fv[s + 2];

        const float s_star = s0 + fmaxf(v * Thw + v * delv * inv2sab, 0.0f);
        const float r  = v * inv_v0;
        const float r2 = r * r;
        const float q  = s_star / gap;
        const float a_calc = pa * (1.0f - r2 * r2 - q * q);
        const float v2 = v + a_calc * DT;
        const float a_t = (v2 <= 0.0f) ? (-v * inv_dt) : a_calc;

        v    = v + a_t * DT;
        delv = v - lvv_i;
        y    = y + v * DT;
        gap  = lvY_i - y;
        sOut[t * STEPS + s] = y;
    }
    __syncthreads();

    // --- fully-coalesced output store: block region contiguous, 16B aligned
    // (256 rows * 30 floats * 4 B = 30720 B per block, 30720 % 16 == 0) ---
    const float4* so4 = (const float4*)sOut;
    float4* go4 = (float4*)(out + (long)blockIdx.x * RPB * STEPS);
    #pragma unroll
    for (int k = t; k < RPB * STEPS / 4; k += THREADS)   // 1920 float4
        go4[k] = so4[k];
}

extern "C" void kernel_launch(void* const* d_in, const int* in_sizes, int n_in,
                              void* d_out, int out_size, void* d_ws, size_t ws_size,
                              hipStream_t stream) {
    const float* params    = (const float*)d_in[0];
    const float* sv_v1     = (const float*)d_in[1];
    const float* h1        = (const float*)d_in[2];
    const float* dv1       = (const float*)d_in[3];
    const float* sv_Y1     = (const float*)d_in[4];
    const float* lv_Y_seq1 = (const float*)d_in[5];
    const float* lv_v_seq1 = (const float*)d_in[6];
    float* out = (float*)d_out;

    const int blocks = B_ROWS / RPB;   // 1024
    traj_idm_kernel<<<blocks, THREADS, 0, stream>>>(
        params, sv_v1, h1, dv1, sv_Y1, lv_Y_seq1, lv_v_seq1, out);
}

// Round 2
// 378.038 us; speedup vs baseline: 1.0041x; 1.0041x over previous
//
#include <hip/hip_runtime.h>

#define B_ROWS 262144
#define T_COLS 80
#define STEPS 30
#define DT 0.1f
#define RPB 256          // one row per thread
#define THREADS 256

__global__ __launch_bounds__(THREADS) void traj_idm_kernel(
    const float* __restrict__ params,
    const float* __restrict__ sv_v1,
    const float* __restrict__ h1,
    const float* __restrict__ dv1,
    const float* __restrict__ sv_Y1,
    const float* __restrict__ lv_Y_seq1,
    const float* __restrict__ lv_v_seq1,
    float* __restrict__ out)
{
    // LDS only for output transpose (coalesced store). 30.7 KB.
    __shared__ __align__(16) float sOut[RPB * STEPS];

    const int t = threadIdx.x;
    const long row = (long)blockIdx.x * RPB + t;
    const long rb  = row * T_COLS;

    // --- issue ALL global loads up front, then force materialization so the
    // compiler cannot sink them into the recurrence (VGPR=44 last round showed
    // it serialized the loads; we need ~20 in flight per lane for MLP). ---
    const float4* py = (const float4*)(lv_Y_seq1 + rb + 48);   // 16B aligned
    const float4* pv = (const float4*)(lv_v_seq1 + rb + 48);

    // scalar col-49 gathers (needed first by the recurrence): issue first
    float v    = sv_v1[rb + 49];
    float gap  = h1   [rb + 49];
    float delv = dv1  [rb + 49];
    float y    = sv_Y1[rb + 49];

    float4 ry[8], rv[8];
    #pragma unroll
    for (int i = 0; i < 8; ++i) { ry[i] = py[i]; rv[i] = pv[i]; }

    // keep-alive barrier: all 64+4 values must be live HERE -> 20 loads issue
    // back-to-back, one drain, full memory-level parallelism per wave.
    #pragma unroll
    for (int i = 0; i < 8; ++i) {
        asm volatile("" ::
            "v"(ry[i].x), "v"(ry[i].y), "v"(ry[i].z), "v"(ry[i].w),
            "v"(rv[i].x), "v"(rv[i].y), "v"(rv[i].z), "v"(rv[i].w));
    }
    asm volatile("" :: "v"(v), "v"(gap), "v"(delv), "v"(y));

    float fy[32], fv[32];
    #pragma unroll
    for (int i = 0; i < 8; ++i) {
        fy[4*i + 0] = ry[i].x;  fy[4*i + 1] = ry[i].y;
        fy[4*i + 2] = ry[i].z;  fy[4*i + 3] = ry[i].w;
        fv[4*i + 0] = rv[i].x;  fv[4*i + 1] = rv[i].y;
        fv[4*i + 2] = rv[i].z;  fv[4*i + 3] = rv[i].w;
    }

    const float s0  = params[0];
    const float Thw = params[1];
    const float pa  = params[2];
    const float pb  = params[3];
    const float v0  = params[4];
    const float inv2sab = 1.0f / (2.0f * sqrtf(pa * pb));
    const float inv_v0  = 1.0f / v0;
    const float inv_dt  = 1.0f / DT;

    // --- 30-step IDM recurrence, fully unrolled, all indices static ---
    #pragma unroll
    for (int s = 0; s < STEPS; ++s) {
        const float lvY_i = fy[s + 2];   // col 50+s (48-based local index)
        const float lvv_i = fv[s + 2];

        const float s_star = s0 + fmaxf(v * Thw + v * delv * inv2sab, 0.0f);
        const float r  = v * inv_v0;
        const float r2 = r * r;
        const float q  = s_star / gap;
        const float a_calc = pa * (1.0f - r2 * r2 - q * q);
        const float v2 = v + a_calc * DT;
        const float a_t = (v2 <= 0.0f) ? (-v * inv_dt) : a_calc;

        v    = v + a_t * DT;
        delv = v - lvv_i;
        y    = y + v * DT;
        gap  = lvY_i - y;
        sOut[t * STEPS + s] = y;
    }
    __syncthreads();

    // --- fully-coalesced output store: block region contiguous, 16B aligned
    // (256 rows * 30 floats * 4 B = 30720 B per block) ---
    const float4* so4 = (const float4*)sOut;
    float4* go4 = (float4*)(out + (long)blockIdx.x * RPB * STEPS);
    #pragma unroll
    for (int k = t; k < RPB * STEPS / 4; k += THREADS)   // 1920 float4
        go4[k] = so4[k];
}

extern "C" void kernel_launch(void* const* d_in, const int* in_sizes, int n_in,
                              void* d_out, int out_size, void* d_ws, size_t ws_size,
                              hipStream_t stream) {
    const float* params    = (const float*)d_in[0];
    const float* sv_v1     = (const float*)d_in[1];
    const float* h1        = (const float*)d_in[2];
    const float* dv1       = (const float*)d_in[3];
    const float* sv_Y1     = (const float*)d_in[4];
    const float* lv_Y_seq1 = (const float*)d_in[5];
    const float* lv_v_seq1 = (const float*)d_in[6];
    float* out = (float*)d_out;

    const int blocks = B_ROWS / RPB;   // 1024
    traj_idm_kernel<<<blocks, THREADS, 0, stream>>>(
        params, sv_v1, h1, dv1, sv_Y1, lv_Y_seq1, lv_v_seq1, out);
}

// Round 3
// 377.810 us; speedup vs baseline: 1.0047x; 1.0006x over previous
//
#include <hip/hip_runtime.h>

#define B_ROWS 262144
#define T_COLS 80
#define STEPS 30
#define DT 0.1f
#define RPB 256
#define THREADS 256
#define PITCH 33   // 32 staged cols + 1 pad -> conflict-free column reads

__global__ __launch_bounds__(THREADS) void traj_idm_kernel(
    const float* __restrict__ params,
    const float* __restrict__ sv_v1,
    const float* __restrict__ h1,
    const float* __restrict__ dv1,
    const float* __restrict__ sv_Y1,
    const float* __restrict__ lv_Y_seq1,
    const float* __restrict__ lv_v_seq1,
    float* __restrict__ out)
{
    // sY doubles as the output buffer: y[s] overwrites the dead sY[t][2+s]
    // slot after it is consumed, so no separate sOut (LDS = 71.7 KB -> 2 blk/CU).
    __shared__ float sY[RPB][PITCH];
    __shared__ float sV[RPB][PITCH];
    __shared__ float gV[RPB], gH[RPB], gD[RPB], gY[RPB];

    const int t = threadIdx.x;
    const long r0 = (long)blockIdx.x * RPB;

    // ---- A: col-49 gathers, COALESCED. col 49 of row r lives in the 64B
    // line spanning cols 48..63; 4 lanes x float4 cover it fully. Every read
    // instruction presents 16 fully-used lines (4-lane merged quads) to the
    // TA instead of 64 discrete 320B-strided addresses. ----
    float4 ga0[4], ga1[4], ga2[4], ga3[4];
    #pragma unroll
    for (int i = 0; i < 4; ++i) {
        const int idx = i * THREADS + t;          // 0..1023
        const int row = idx >> 2;
        const int sub = idx & 3;
        const long off = (r0 + row) * T_COLS + 48 + sub * 4;
        ga0[i] = *(const float4*)(sv_v1 + off);
        ga1[i] = *(const float4*)(h1    + off);
        ga2[i] = *(const float4*)(dv1   + off);
        ga3[i] = *(const float4*)(sv_Y1 + off);
    }

    // ---- B: lv tail staging, COALESCED (8 lanes x float4 = one row's 128B
    // tail; 16 fully-used lines per wave instruction). ----
    float4 ry[8], rv[8];
    #pragma unroll
    for (int i = 0; i < 8; ++i) {
        const int idx = i * THREADS + t;          // 0..2047
        const int row = idx >> 3;
        const int sub = idx & 7;
        const long off = (r0 + row) * T_COLS + 48 + sub * 4;
        ry[i] = *(const float4*)(lv_Y_seq1 + off);
        rv[i] = *(const float4*)(lv_v_seq1 + off);
    }

    // Keep ALL components of the gather lines alive: without this the
    // compiler narrows the float4 to the single used .y component and
    // de-coalesces the load back into a 64-line scatter.
    #pragma unroll
    for (int i = 0; i < 4; ++i) {
        asm volatile("" :: "v"(ga0[i].x), "v"(ga0[i].y), "v"(ga0[i].z), "v"(ga0[i].w));
        asm volatile("" :: "v"(ga1[i].x), "v"(ga1[i].y), "v"(ga1[i].z), "v"(ga1[i].w));
        asm volatile("" :: "v"(ga2[i].x), "v"(ga2[i].y), "v"(ga2[i].z), "v"(ga2[i].w));
        asm volatile("" :: "v"(ga3[i].x), "v"(ga3[i].y), "v"(ga3[i].z), "v"(ga3[i].w));
    }

    // ---- LDS writes (single vmcnt drain region) ----
    #pragma unroll
    for (int i = 0; i < 8; ++i) {
        const int idx = i * THREADS + t;
        const int row = idx >> 3;
        const int c   = (idx & 7) * 4;
        sY[row][c+0] = ry[i].x; sY[row][c+1] = ry[i].y;
        sY[row][c+2] = ry[i].z; sY[row][c+3] = ry[i].w;
        sV[row][c+0] = rv[i].x; sV[row][c+1] = rv[i].y;
        sV[row][c+2] = rv[i].z; sV[row][c+3] = rv[i].w;
    }
    #pragma unroll
    for (int i = 0; i < 4; ++i) {
        const int idx = i * THREADS + t;
        const int row = idx >> 2;
        if ((idx & 3) == 0) {            // this lane's float4 = cols 48..51; .y = col 49
            gV[row] = ga0[i].y;
            gH[row] = ga1[i].y;
            gD[row] = ga2[i].y;
            gY[row] = ga3[i].y;
        }
    }
    __syncthreads();

    // ---- compute: 30-step IDM recurrence, one thread per row ----
    {
        float v    = gV[t];
        float gap  = gH[t];
        float delv = gD[t];
        float y    = gY[t];

        const float s0  = params[0];
        const float Thw = params[1];
        const float pa  = params[2];
        const float pb  = params[3];
        const float v0  = params[4];
        const float inv2sab = 1.0f / (2.0f * sqrtf(pa * pb));
        const float inv_v0  = 1.0f / v0;
        const float inv_dt  = 1.0f / DT;

        #pragma unroll
        for (int s = 0; s < STEPS; ++s) {
            const float lvY_i = sY[t][2 + s];   // col 50+s
            const float lvv_i = sV[t][2 + s];

            const float s_star = s0 + fmaxf(v * Thw + v * delv * inv2sab, 0.0f);
            const float r  = v * inv_v0;
            const float r2 = r * r;
            const float q  = s_star / gap;
            const float a_calc = pa * (1.0f - r2 * r2 - q * q);
            const float v2 = v + a_calc * DT;
            const float a_t = (v2 <= 0.0f) ? (-v * inv_dt) : a_calc;

            v    = v + a_t * DT;
            delv = v - lvv_i;
            y    = y + v * DT;
            gap  = lvY_i - y;
            sY[t][2 + s] = y;                   // dead slot -> output buffer
        }
    }
    __syncthreads();

    // ---- coalesced float4 store from the recycled sY buffer ----
    // block output region = 256 rows * 30 floats = 7680 floats, 16B aligned.
    float4* go4 = (float4*)(out + r0 * STEPS);
    #pragma unroll 1
    for (int k = t; k < RPB * STEPS / 4; k += THREADS) {   // 1920 float4
        const int e = 4 * k;
        float4 o;
        o.x = sY[(e+0)/30][2 + (e+0)%30];
        o.y = sY[(e+1)/30][2 + (e+1)%30];
        o.z = sY[(e+2)/30][2 + (e+2)%30];
        o.w = sY[(e+3)/30][2 + (e+3)%30];
        go4[k] = o;
    }
}

extern "C" void kernel_launch(void* const* d_in, const int* in_sizes, int n_in,
                              void* d_out, int out_size, void* d_ws, size_t ws_size,
                              hipStream_t stream) {
    const float* params    = (const float*)d_in[0];
    const float* sv_v1     = (const float*)d_in[1];
    const float* h1        = (const float*)d_in[2];
    const float* dv1       = (const float*)d_in[3];
    const float* sv_Y1     = (const float*)d_in[4];
    const float* lv_Y_seq1 = (const float*)d_in[5];
    const float* lv_v_seq1 = (const float*)d_in[6];
    float* out = (float*)d_out;

    const int blocks = B_ROWS / RPB;   // 1024
    traj_idm_kernel<<<blocks, THREADS, 0, stream>>>(
        params, sv_v1, h1, dv1, sv_Y1, lv_Y_seq1, lv_v_seq1, out);
}